// Round 3
// baseline (525.196 us; speedup 1.0000x reference)
//
#include <hip/hip_runtime.h>
#include <stdint.h>

#define N_ROWS 16384
#define K_DIM  2048
#define N_OUT  2048
#define NGROUPS 8
#define BM 128
#define BN 128
#define BK 32
#define MAX_Y 136   // sum ceil(n_g/128) <= 16384/128 + 8

typedef short s16x8 __attribute__((ext_vector_type(8)));   // 8 bf16 bit-patterns (guide-verified frag type)
typedef float f32x4 __attribute__((ext_vector_type(4)));

// RNE float -> bf16 (bit-level)
__device__ __forceinline__ unsigned short f2bf(float f) {
    unsigned int u = __float_as_uint(f);
    u += 0x7fffu + ((u >> 16) & 1u);
    return (unsigned short)(u >> 16);
}

__global__ void convert_kernel(const float* __restrict__ src,
                               unsigned short* __restrict__ dst, int n) {
    int stride = gridDim.x * blockDim.x;
    for (int i = blockIdx.x * blockDim.x + threadIdx.x; i * 4 < n; i += stride) {
        float4 v = *(const float4*)(src + (size_t)i * 4);
        ushort4 o;
        o.x = f2bf(v.x); o.y = f2bf(v.y); o.z = f2bf(v.z); o.w = f2bf(v.w);
        *(ushort4*)(dst + (size_t)i * 4) = o;
    }
}

__device__ __forceinline__ int lower_bound_g(const int* __restrict__ gi, int g) {
    int lo = 0, hi = N_ROWS;
    while (lo < hi) { int mid = (lo + hi) >> 1; if (gi[mid] < g) lo = mid + 1; else hi = mid; }
    return lo;
}

#define GLDS16(gp, lp) \
    __builtin_amdgcn_global_load_lds((__attribute__((address_space(1))) void*)(gp), \
                                     (__attribute__((address_space(3))) void*)(lp), 16, 0, 0)

__global__ __launch_bounds__(256) void grouped_gemm(
    const unsigned short* __restrict__ xb,   // [N, K] bf16
    const unsigned short* __restrict__ wb,   // [G, N_OUT, K] bf16
    const float* __restrict__ bias,          // [G, N_OUT] fp32
    const int* __restrict__ gi,              // sorted [N]
    float* __restrict__ out)                 // [N, N_OUT] fp32
{
    // In-kernel group boundaries (uniform across block; broadcast loads, L1/L2-cached)
    int s[NGROUPS + 1];
    s[0] = 0; s[NGROUPS] = N_ROWS;
    #pragma unroll
    for (int g = 1; g < NGROUPS; g++) s[g] = lower_bound_g(gi, g);

    int by = blockIdx.y;
    int row0 = -1, g = 0, nrows = 0, c = 0;
    #pragma unroll
    for (int gg = 0; gg < NGROUPS; gg++) {
        int n = s[gg + 1] - s[gg];
        int tiles = (n + BM - 1) / BM;
        if (row0 < 0 && by < c + tiles) {
            g = gg;
            row0 = s[gg] + (by - c) * BM;
            nrows = n - (by - c) * BM; if (nrows > BM) nrows = BM;
        }
        c += tiles;
    }
    if (row0 < 0) return;   // uniform early-out, before any barrier
    int col0 = blockIdx.x * BN;

    __shared__ unsigned short As[BM * BK];   // [m][k], row = 32 elems (64 B)
    __shared__ unsigned short Bs[BN * BK];   // [n][k]

    int t = threadIdx.x;
    int w = t >> 6, l = t & 63;
    int la = l & 15, quad = l >> 4;
    int wm = w >> 1, wn = w & 1;

    // Staging: wave w covers rows [w*16, w*16+16), lane l -> row w*16 + l/4, kcol (l%4)*8
    int arow = w * 16 + (l >> 2);
    int kcol = (l & 3) * 8;
    int ar0 = min(row0 + arow,      N_ROWS - 1);   // clamp for partial last tile
    int ar1 = min(row0 + 64 + arow, N_ROWS - 1);
    const unsigned short* gA0 = xb + (size_t)ar0 * K_DIM + kcol;
    const unsigned short* gA1 = xb + (size_t)ar1 * K_DIM + kcol;
    const unsigned short* gB0 = wb + ((size_t)g * N_OUT + col0 + arow) * K_DIM + kcol;
    const unsigned short* gB1 = gB0 + (size_t)64 * K_DIM;
    unsigned short* lA = As + w * 512;   // wave-uniform LDS base; lane lands at +16B*l
    unsigned short* lB = Bs + w * 512;

    f32x4 acc[4][4];
    #pragma unroll
    for (int i = 0; i < 4; i++)
        #pragma unroll
        for (int j = 0; j < 4; j++)
            acc[i][j] = (f32x4){0.f, 0.f, 0.f, 0.f};

    for (int k0 = 0; k0 < K_DIM; k0 += BK) {
        GLDS16(gA0 + k0, lA);
        GLDS16(gA1 + k0, lA + 2048);
        GLDS16(gB0 + k0, lB);
        GLDS16(gB1 + k0, lB + 2048);
        __syncthreads();   // drains vmcnt(0) then barrier -> LDS tiles valid

        s16x8 af[4], bf_[4];
        #pragma unroll
        for (int mi = 0; mi < 4; mi++)
            af[mi] = *(const s16x8*)&As[(wm * 64 + mi * 16 + la) * BK + quad * 8];
        #pragma unroll
        for (int ni = 0; ni < 4; ni++)
            bf_[ni] = *(const s16x8*)&Bs[(wn * 64 + ni * 16 + la) * BK + quad * 8];

        #pragma unroll
        for (int mi = 0; mi < 4; mi++)
            #pragma unroll
            for (int ni = 0; ni < 4; ni++)
                acc[mi][ni] = __builtin_amdgcn_mfma_f32_16x16x32_bf16(
                    af[mi], bf_[ni], acc[mi][ni], 0, 0, 0);
        __syncthreads();   // all waves done reading before next overwrite
    }

    // Epilogue: C/D layout col=lane&15, row=quad*4+reg (m89/m91-verified); fused bias.
    int row_end = row0 + nrows;
    float bv[4];
    #pragma unroll
    for (int ni = 0; ni < 4; ni++)
        bv[ni] = bias[g * N_OUT + col0 + wn * 64 + ni * 16 + la];
    #pragma unroll
    for (int mi = 0; mi < 4; mi++) {
        int rbase = row0 + wm * 64 + mi * 16 + quad * 4;
        #pragma unroll
        for (int r = 0; r < 4; r++) {
            int row = rbase + r;
            if (row < row_end) {
                float* op = out + (size_t)row * N_OUT + col0 + wn * 64 + la;
                #pragma unroll
                for (int ni = 0; ni < 4; ni++)
                    op[ni * 16] = acc[mi][ni][r] + bv[ni];
            }
        }
    }
}

// Last-resort fallback (ws too small for bf16 copies): correct fp32 path.
__global__ void naive_kernel(const float* __restrict__ x, const float* __restrict__ wgt,
                             const float* __restrict__ bias, const int* __restrict__ gi,
                             float* __restrict__ out) {
    int row = blockIdx.x;
    int g = gi[row] & (NGROUPS - 1);
    __shared__ float xs[K_DIM];
    for (int i = threadIdx.x; i < K_DIM; i += 256) xs[i] = x[(size_t)row * K_DIM + i];
    __syncthreads();
    for (int c = threadIdx.x; c < N_OUT; c += 256) {
        const float* wr = wgt + ((size_t)g * N_OUT + c) * K_DIM;
        float s = 0.f;
        for (int k = 0; k < K_DIM; k++) s += xs[k] * wr[k];
        out[(size_t)row * N_OUT + c] = s + bias[g * N_OUT + c];
    }
}

extern "C" void kernel_launch(void* const* d_in, const int* in_sizes, int n_in,
                              void* d_out, int out_size, void* d_ws, size_t ws_size,
                              hipStream_t stream) {
    const float* x    = (const float*)d_in[0];
    const float* wgt  = (const float*)d_in[1];
    const float* bias = (const float*)d_in[2];
    const int*   gi   = (const int*)d_in[3];
    float* out = (float*)d_out;

    const size_t xb_bytes = (size_t)N_ROWS * K_DIM * 2;           // 64 MiB
    const size_t wb_bytes = (size_t)NGROUPS * N_OUT * K_DIM * 2;  // 64 MiB
    const size_t need = xb_bytes + wb_bytes;                      // exactly 128 MiB

    if (ws_size < need) {
        naive_kernel<<<dim3(N_ROWS), dim3(256), 0, stream>>>(x, wgt, bias, gi, out);
        return;
    }

    unsigned short* xb = (unsigned short*)d_ws;
    unsigned short* wb = (unsigned short*)((char*)d_ws + xb_bytes);

    convert_kernel<<<dim3(8192), dim3(256), 0, stream>>>(x,   xb, N_ROWS * K_DIM);
    convert_kernel<<<dim3(8192), dim3(256), 0, stream>>>(wgt, wb, NGROUPS * N_OUT * K_DIM);
    grouped_gemm<<<dim3(N_OUT / BN, MAX_Y), dim3(256), 0, stream>>>(
        xb, wb, bias, gi, out);
}